// Round 12
// baseline (228.853 us; speedup 1.0000x reference)
//
#include <hip/hip_runtime.h>
#include <stdint.h>

// B=16, C=64, H=128, W=128, HX=HY=64. All I/O fp32.
// Pipeline (3 kernels):
//   k_proj0 : pre_x[t=w][seq=(b,h)][j] (f16, incl bias) = Wihx·x + b   (bf16 hi/lo)
//   k_scan<0>: X recurrence; FUSED Y-projection -> pre_y[t=h][seq=(b,w)][j] (f16, incl bias)
//   k_scan<1>: Y recurrence -> out[b][j][h][w] fp32
// d_ws: pre_x (33.5MB) + pre_y (33.5MB) = 67MB.
// ROUND 12: r10/r11 failures were NOT a race: identical absmax (1.7265625)
// across two different barrier implementations = deterministic data bug.
// Found it: pair-loop preload used LOADSLAB(psA, G0+48) -- psA then held
// t=48..63 while TICKS(psA, G0+32) consumed it as t=32..47 (off by 16).
// Fixed to G0+32. The asm-unit LDS exchange from r11 is kept (safe against
// IR reordering across s_barrier, which is IntrNoMem):
//   {ds_write_b64; s_waitcnt lgkmcnt(0); s_barrier}   (one asm volatile)
//   {ds_read_b128 x2; s_waitcnt lgkmcnt(0)}           (one asm volatile)
// vmcnt never drains at barriers -> slab loads (psA/psB dbuf) and burst
// stores flow across ticks. Math bit-identical to the 227.8us champion:
// absmax must be exactly 0.00390625.
// Dead ends: co-residency (r1/3/5), multi-chain ILP (r2/4/8), single-wave
// (r7), X->Y fusion (derived: zero overlap).

#define TLEN 128
#define NSEQ 2048
#define PSH (NSEQ*64)   // f16 elems per t-slice
#define GT 16           // steps per group

typedef __bf16   bf16x8 __attribute__((ext_vector_type(8)));
typedef _Float16 f16x8  __attribute__((ext_vector_type(8)));
typedef _Float16 f16x4  __attribute__((ext_vector_type(4)));
typedef float    f32x4  __attribute__((ext_vector_type(4)));
typedef unsigned short u16x4 __attribute__((ext_vector_type(4)));
typedef unsigned short u16x8 __attribute__((ext_vector_type(8)));

static __device__ __forceinline__ unsigned int fbits(float f){
    union { float f; unsigned int u; } v; v.f = f; return v.u;
}
static __device__ __forceinline__ float ubits(unsigned int u){
    union { unsigned int u; float f; } v; v.u = u; return v.f;
}
static __device__ __forceinline__ float bf2f(unsigned short s){ return ubits(((unsigned int)s) << 16); }
static __device__ __forceinline__ unsigned short f2bf(float f){
    unsigned int u = fbits(f);
    return (unsigned short)((u + 0x7FFFu + ((u >> 16) & 1u)) >> 16);
}
static __device__ __forceinline__ __bf16 us2b(unsigned short s){
    union { unsigned short u; __bf16 b; } v; v.u = s; return v.b;
}
static __device__ __forceinline__ unsigned short h2us(_Float16 h){
    union { _Float16 h; unsigned short s; } v; v.h = h; return v.s;
}
struct bfpair { __bf16 hi, lo; };
static __device__ __forceinline__ bfpair splitf(float f){   // RNE split (weights, once)
    unsigned short h = f2bf(f);
    bfpair r; r.hi = us2b(h); r.lo = us2b(f2bf(f - bf2f(h))); return r;
}
static __device__ __forceinline__ float fast_tanh(float x){
    float e = __builtin_amdgcn_exp2f(x * 2.8853900817779268f);
    return 1.0f - 2.0f * __builtin_amdgcn_rcpf(e + 1.0f);
}

// ---------------------------------------------------------------------------
// k_proj0: pre_x[w][b*128+h][j] = f16( sum_c x[b][c][h][w]*Wihx[j][c] + bias )
// bf16 hi/lo 3-term MFMA. Block 256thr/4 waves; wave: 32 rows (= 2 mi-tiles
// of 16 consecutive w, fixed seq) x 64 j. Stores via per-wave LDS transpose
// (round-9 version, proven).
__global__ __launch_bounds__(256) void k_proj0(const float* __restrict__ A,
                                               const float* __restrict__ Wih,
                                               const float* __restrict__ b1,
                                               const float* __restrict__ b2,
                                               _Float16* __restrict__ pre){
    __shared__ alignas(16) unsigned short lds_t[2][4][16][64];  // [mi][wave][w'][j]
    int lane = threadIdx.x & 63;
    int wv   = threadIdx.x >> 6;
    int q    = lane >> 4, l15 = lane & 15;

    bf16x8 Whi[4][2], Wlo[4][2];
#pragma unroll
    for (int n = 0; n < 4; n++)
#pragma unroll
        for (int kc = 0; kc < 2; kc++){
            const float* p = Wih + (n * 16 + l15) * 64 + kc * 32 + q * 8;
#pragma unroll
            for (int i = 0; i < 8; i++){
                bfpair s = splitf(p[i]);
                Whi[n][kc][i] = s.hi; Wlo[n][kc][i] = s.lo;
            }
        }
    float bias[4];
#pragma unroll
    for (int n = 0; n < 4; n++){
        int j = n * 16 + l15;
        bias[n] = b1[j] + b2[j];
    }

    int row0 = blockIdx.x * 128 + wv * 32;

    float av[2][2][8];
#pragma unroll
    for (int mi = 0; mi < 2; mi++){
        int r = row0 + mi * 16 + l15;
        int b = r >> 14, hw = r & 16383;
        const float* xb = A + (size_t)b * 1048576 + hw;
#pragma unroll
        for (int kc = 0; kc < 2; kc++)
#pragma unroll
            for (int i = 0; i < 8; i++)
                av[mi][kc][i] = xb[(size_t)(kc * 32 + q * 8 + i) * 16384];
    }

#pragma unroll
    for (int mi = 0; mi < 2; mi++){
        int rb = row0 + mi * 16;
        bf16x8 Ahi[2], Alo[2];
#pragma unroll
        for (int kc = 0; kc < 2; kc++)
#pragma unroll
            for (int i = 0; i < 8; i++){
                bfpair s = splitf(av[mi][kc][i]);
                Ahi[kc][i] = s.hi; Alo[kc][i] = s.lo;
            }
        f32x4 acc[4];
#pragma unroll
        for (int n = 0; n < 4; n++) acc[n] = (f32x4){bias[n], bias[n], bias[n], bias[n]};
#pragma unroll
        for (int n = 0; n < 4; n++)
#pragma unroll
            for (int kc = 0; kc < 2; kc++){
                acc[n] = __builtin_amdgcn_mfma_f32_16x16x32_bf16(Ahi[kc], Whi[n][kc], acc[n], 0, 0, 0);
                acc[n] = __builtin_amdgcn_mfma_f32_16x16x32_bf16(Alo[kc], Whi[n][kc], acc[n], 0, 0, 0);
                acc[n] = __builtin_amdgcn_mfma_f32_16x16x32_bf16(Ahi[kc], Wlo[n][kc], acc[n], 0, 0, 0);
            }
        // rows rb..rb+15 share (b,h) = seq; w = (rb&127) + q*4 + rr.
        int bT = rb >> 14, hT = (rb >> 7) & 127, wBase = rb & 127;
        size_t seqOff = (size_t)bT * 128 + hT;
        // stage tile in per-wave LDS: [w' = q*4+rr][j = n*16+l15]
#pragma unroll
        for (int n = 0; n < 4; n++)
#pragma unroll
            for (int rr = 0; rr < 4; rr++)
                lds_t[mi][wv][q * 4 + rr][n * 16 + l15] = h2us((_Float16)acc[n][rr]);
        // read back transposed: 8 consecutive lanes = one dense 128B row
#pragma unroll
        for (int k = 0; k < 2; k++){
            int wp = (lane >> 3) + k * 8;
            int j8 = (lane & 7) * 8;
            u16x8 v = *(const u16x8*)&lds_t[mi][wv][wp][j8];
            *(u16x8*)(pre + ((size_t)(wBase + wp) * NSEQ + seqOff) * 64 + j8) = v;
        }
    }
}

// ---------------------------------------------------------------------------
// k_scan<PASS>: h_t = tanh(pre_t + Whh h_{t-1}), 128 blocks x 4 waves.
// Round-6 math bit-identical; asm-unit LDS exchange + raw barrier (vmcnt
// flows) + psA/psB slab double-buffer (preload index FIXED: G0+32).

#define PARS 2048u   // sizeof(hbuf[0]) = 16*64*2 bytes

#define LOADSLAB(PS, GB)                                       \
    _Pragma("unroll")                                          \
    for (int u_ = 0; u_ < GT; u_++)                            \
        PS[u_] = *(const f16x4*)(pb + (size_t)((GB) + u_) * PSH);

#define TICKS(PS, GB)                                                           \
    _Pragma("unroll")                                                           \
    for (int u = 0; u < GT; u++){                                               \
        int t = (GB) + u;                                                       \
        f32x4 a = (f32x4){(float)PS[u][0], (float)PS[u][1],                     \
                          (float)PS[u][2], (float)PS[u][3]};                    \
        a = __builtin_amdgcn_mfma_f32_16x16x32_f16(Af[0], Bf[0], a, 0, 0, 0);   \
        a = __builtin_amdgcn_mfma_f32_16x16x32_f16(Af[1], Bf[1], a, 0, 0, 0);   \
        if constexpr (PASS == 0){                                               \
            f32x4 y = biasy;                                                    \
            y = __builtin_amdgcn_mfma_f32_16x16x32_f16(Yf[0], Bf[0], y, 0, 0, 0); \
            y = __builtin_amdgcn_mfma_f32_16x16x32_f16(Yf[1], Bf[1], y, 0, 0, 0); \
            _Pragma("unroll")                                                   \
            for (int r = 0; r < 4; r++)                                         \
                prey_st[u][r] = h2us((_Float16)y[r]);                           \
        }                                                                       \
        u16x4 h4;                                                               \
        _Pragma("unroll")                                                       \
        for (int r = 0; r < 4; r++){                                            \
            float tv = fast_tanh(a[r]);                                         \
            if constexpr (PASS == 1) outst[u][r] = tv;                          \
            h4[r] = h2us((_Float16)tv);                                         \
        }                                                                       \
        unsigned int pofs = (unsigned int)((t & 1) ? PARS : 0u);                \
        unsigned int wa = wj_off + pofs;                                        \
        asm volatile("ds_write_b64 %0, %1\n\t"                                  \
                     "s_waitcnt lgkmcnt(0)\n\t"                                 \
                     "s_barrier"                                                \
                     :: "v"(wa), "v"(h4) : "memory");                           \
        unsigned int ra0 = rj0_off + pofs;                                      \
        unsigned int ra1 = rj1_off + pofs;                                      \
        f16x8 nb0, nb1;                                                         \
        asm volatile("ds_read_b128 %0, %2\n\t"                                  \
                     "ds_read_b128 %1, %3\n\t"                                  \
                     "s_waitcnt lgkmcnt(0)"                                     \
                     : "=&v"(nb0), "=&v"(nb1)                                   \
                     : "v"(ra0), "v"(ra1) : "memory");                          \
        __builtin_amdgcn_sched_barrier(0);                                      \
        Bf[0] = nb0; Bf[1] = nb1;                                               \
    }

#define GSTORE(GB)                                                              \
    if constexpr (PASS == 0){                                                   \
        _Pragma("unroll")                                                       \
        for (int u = 0; u < GT; u++){                                           \
            int tp = (GB) - 1 + u;                                              \
            if (tp >= 0)                                                        \
                *(u16x4*)(prey + (spy + tp) * 64 + j0) = prey_st[u];            \
        }                                                                       \
    } else {                                                                    \
        _Pragma("unroll")                                                       \
        for (int u = 0; u < GT; u++)                                            \
            _Pragma("unroll")                                                   \
            for (int r = 0; r < 4; r++)                                         \
                outf[((size_t)(bb * 64 + j0 + r) * TLEN + ((GB) + u)) * 128     \
                     + low7 + l15] = outst[u][r];                               \
    }

template<int PASS>
__global__ __launch_bounds__(256) void k_scan(const _Float16* __restrict__ pre,
                                              const float* __restrict__ Whh,
                                              const float* __restrict__ Wy,
                                              const float* __restrict__ by1,
                                              const float* __restrict__ by2,
                                              _Float16* __restrict__ prey,
                                              float* __restrict__ outf){
    __shared__ alignas(16) unsigned short hbuf[2][16][64];  // [par][seq][j] f16 bits
    int lane = threadIdx.x & 63;
    int wv   = threadIdx.x >> 6;
    int q = lane >> 4, l15 = lane & 15;
    int n0 = blockIdx.x * 16;
    int j0 = wv * 16 + q * 4;

    f16x8 Af[2];
#pragma unroll
    for (int kc = 0; kc < 2; kc++){
        const float* p = Whh + (wv * 16 + l15) * 64 + kc * 32 + q * 8;
#pragma unroll
        for (int i = 0; i < 8; i++)
            Af[kc][i] = (_Float16)p[i];
    }
    f16x8 Yf[2];
    f32x4 biasy = (f32x4){0.f, 0.f, 0.f, 0.f};
    if constexpr (PASS == 0){
#pragma unroll
        for (int kc = 0; kc < 2; kc++){
            const float* p = Wy + (wv * 16 + l15) * 64 + kc * 32 + q * 8;
#pragma unroll
            for (int i = 0; i < 8; i++)
                Yf[kc][i] = (_Float16)p[i];
        }
#pragma unroll
        for (int r = 0; r < 4; r++) biasy[r] = by1[j0 + r] + by2[j0 + r];
    }

    f16x8 Bf[2];
#pragma unroll
    for (int kc = 0; kc < 2; kc++)
#pragma unroll
        for (int i = 0; i < 8; i++) Bf[kc][i] = (_Float16)0.f;

    int bb = n0 >> 7, low7 = n0 & 127;   // PASS0: h0 = low7; PASS1: w0 = low7

    const _Float16* pb = pre + (size_t)(n0 + l15) * 64 + j0;
    size_t spy = (size_t)(low7 + l15) * NSEQ + (size_t)bb * 128;  // PASS0 prey seq base

    int e   = l15 & 7;
    int wj  = (((j0 >> 3) ^ e) << 3) | (j0 & 7);
    int rj0 = ((q)     ^ e) << 3;
    int rj1 = ((4 + q) ^ e) << 3;

    // LDS byte offsets (generic LDS ptr low 32 bits = LDS offset; aperture
    // is 4GB-aligned on gfx9+). wj is 8B-aligned (b64), rj* 16B (b128).
    unsigned int wj_off  = (unsigned int)(uintptr_t)&hbuf[0][l15][wj];
    unsigned int rj0_off = (unsigned int)(uintptr_t)&hbuf[0][l15][rj0];
    unsigned int rj1_off = (unsigned int)(uintptr_t)&hbuf[0][l15][rj1];

    f16x4 psA[GT], psB[GT];
    u16x4 prey_st[GT];
    f32x4 outst[GT];

    // pair-loop: slab for group k issued one full group ahead; raw barriers
    // never drain vmcnt, so slab loads and burst stores flow across ticks.
    // Schedule check: psA@0 | gp0: psB@16, T(psA,0), psA@32, T(psB,16)
    //                        | gp1: psB@48, T(psA,32), psA@64, T(psB,48) ...
    LOADSLAB(psA, 0);
    for (int gp = 0; gp < 4; gp++){
        int G0 = gp * 32;
        LOADSLAB(psB, G0 + 16);
        TICKS(psA, G0);
        GSTORE(G0);
        if (gp < 3) LOADSLAB(psA, G0 + 32);
        TICKS(psB, G0 + 16);
        GSTORE(G0 + 16);
    }
    // tail: pre_y[127] from final B (= h_127)
    if constexpr (PASS == 0){
        f32x4 y = biasy;
        y = __builtin_amdgcn_mfma_f32_16x16x32_f16(Yf[0], Bf[0], y, 0, 0, 0);
        y = __builtin_amdgcn_mfma_f32_16x16x32_f16(Yf[1], Bf[1], y, 0, 0, 0);
        u16x4 pv;
#pragma unroll
        for (int r = 0; r < 4; r++)
            pv[r] = h2us((_Float16)y[r]);
        *(u16x4*)(prey + (spy + (TLEN - 1)) * 64 + j0) = pv;
    }
}

// ---------------------------------------------------------------------------
extern "C" void kernel_launch(void* const* d_in, const int* in_sizes, int n_in,
                              void* d_out, int out_size, void* d_ws, size_t ws_size,
                              hipStream_t stream){
    (void)in_sizes; (void)n_in; (void)out_size; (void)ws_size;
    const float* x    = (const float*)d_in[0];
    const float* Wihx = (const float*)d_in[1];
    const float* Whhx = (const float*)d_in[2];
    const float* bihx = (const float*)d_in[3];
    const float* bhhx = (const float*)d_in[4];
    const float* Wihy = (const float*)d_in[5];
    const float* Whhy = (const float*)d_in[6];
    const float* bihy = (const float*)d_in[7];
    const float* bhhy = (const float*)d_in[8];
    _Float16* prex = (_Float16*)d_ws;                          // 33.5MB
    _Float16* prey = prex + (size_t)NSEQ * TLEN * 64;          // 33.5MB
    float* of = (float*)d_out;

    k_proj0 <<<2048, 256, 0, stream>>>(x, Wihx, bihx, bhhx, prex);
    k_scan<0><<<128, 256, 0, stream>>>(prex, Whhx, Wihy, bihy, bhhy, prey, nullptr);
    k_scan<1><<<128, 256, 0, stream>>>(prey, Whhy, nullptr, nullptr, nullptr, nullptr, of);
}

// Round 13
// 221.502 us; speedup vs baseline: 1.0332x; 1.0332x over previous
//
#include <hip/hip_runtime.h>
#include <stdint.h>

// B=16, C=64, H=128, W=128, HX=HY=64. All I/O fp32.
// Pipeline (3 kernels):
//   k_proj0 : pre_x[t=w][seq=(b,h)][j] (f16, incl bias) = Wihx·x + b   (f16-direct, NEW)
//   k_scan<0>: X recurrence; FUSED Y-projection -> pre_y[t=h][seq=(b,w)][j] (f16, incl bias)
//   k_scan<1>: Y recurrence -> out[b][j][h][w] fp32
// d_ws: pre_x (33.5MB) + pre_y (33.5MB) = 67MB.
// ROUND 13: scans REVERTED to round-9 champion (__syncthreads; r12 proved
// the vmcnt drain was never the cost: raw barrier = 50->54us regression;
// 388ns/tick is intrinsic barrier+LDS+dep-chain). proj0 converted to f16-
// DIRECT MFMA (the round-6 trick, unapplied until now): 24->8 MFMA per
// mi-tile, all splitf VALU (~600 ops/wave) deleted. Error budget: +~2^-8
// on top of 0.0039, threshold 0.0191 -> fits. LDS-transpose store kept.
// Dead ends: co-residency (r1/3/5), multi-chain ILP (r2/4/8), single-wave
// (r7), X->Y fusion (derived), raw-barrier/vmcnt (r12: regression).

#define TLEN 128
#define NSEQ 2048
#define PSH (NSEQ*64)   // f16 elems per t-slice
#define GT 16           // steps per group

typedef __bf16   bf16x8 __attribute__((ext_vector_type(8)));
typedef _Float16 f16x8  __attribute__((ext_vector_type(8)));
typedef _Float16 f16x4  __attribute__((ext_vector_type(4)));
typedef float    f32x4  __attribute__((ext_vector_type(4)));
typedef unsigned short u16x4 __attribute__((ext_vector_type(4)));
typedef unsigned short u16x8 __attribute__((ext_vector_type(8)));

static __device__ __forceinline__ unsigned int fbits(float f){
    union { float f; unsigned int u; } v; v.f = f; return v.u;
}
static __device__ __forceinline__ float ubits(unsigned int u){
    union { unsigned int u; float f; } v; v.u = u; return v.f;
}
static __device__ __forceinline__ unsigned short h2us(_Float16 h){
    union { _Float16 h; unsigned short s; } v; v.h = h; return v.s;
}
static __device__ __forceinline__ float fast_tanh(float x){
    float e = __builtin_amdgcn_exp2f(x * 2.8853900817779268f);
    return 1.0f - 2.0f * __builtin_amdgcn_rcpf(e + 1.0f);
}

// ---------------------------------------------------------------------------
// k_proj0: pre_x[w][b*128+h][j] = f16( sum_c x[b][c][h][w]*Wihx[j][c] + bias )
// f16-direct MFMA (fp32 accum). Block 256thr/4 waves; wave: 32 rows (= 2
// mi-tiles of 16 consecutive w, fixed seq) x 64 j. Stores via per-wave LDS
// transpose: each mi-tile (16w x 64j) staged, read back u16x8, stored as
// dense 128B rows (2 dwordx4 bursts per tile).
__global__ __launch_bounds__(256) void k_proj0(const float* __restrict__ A,
                                               const float* __restrict__ Wih,
                                               const float* __restrict__ b1,
                                               const float* __restrict__ b2,
                                               _Float16* __restrict__ pre){
    __shared__ alignas(16) unsigned short lds_t[2][4][16][64];  // [mi][wave][w'][j]
    int lane = threadIdx.x & 63;
    int wv   = threadIdx.x >> 6;
    int q    = lane >> 4, l15 = lane & 15;

    f16x8 Wf[4][2];
#pragma unroll
    for (int n = 0; n < 4; n++)
#pragma unroll
        for (int kc = 0; kc < 2; kc++){
            const float* p = Wih + (n * 16 + l15) * 64 + kc * 32 + q * 8;
#pragma unroll
            for (int i = 0; i < 8; i++)
                Wf[n][kc][i] = (_Float16)p[i];
        }
    float bias[4];
#pragma unroll
    for (int n = 0; n < 4; n++){
        int j = n * 16 + l15;
        bias[n] = b1[j] + b2[j];
    }

    int row0 = blockIdx.x * 128 + wv * 32;

    float av[2][2][8];
#pragma unroll
    for (int mi = 0; mi < 2; mi++){
        int r = row0 + mi * 16 + l15;
        int b = r >> 14, hw = r & 16383;
        const float* xb = A + (size_t)b * 1048576 + hw;
#pragma unroll
        for (int kc = 0; kc < 2; kc++)
#pragma unroll
            for (int i = 0; i < 8; i++)
                av[mi][kc][i] = xb[(size_t)(kc * 32 + q * 8 + i) * 16384];
    }

#pragma unroll
    for (int mi = 0; mi < 2; mi++){
        int rb = row0 + mi * 16;
        f16x8 Af[2];
#pragma unroll
        for (int kc = 0; kc < 2; kc++)
#pragma unroll
            for (int i = 0; i < 8; i++)
                Af[kc][i] = (_Float16)av[mi][kc][i];
        f32x4 acc[4];
#pragma unroll
        for (int n = 0; n < 4; n++) acc[n] = (f32x4){bias[n], bias[n], bias[n], bias[n]};
#pragma unroll
        for (int n = 0; n < 4; n++)
#pragma unroll
            for (int kc = 0; kc < 2; kc++)
                acc[n] = __builtin_amdgcn_mfma_f32_16x16x32_f16(Af[kc], Wf[n][kc], acc[n], 0, 0, 0);
        // rows rb..rb+15 share (b,h) = seq; w = (rb&127) + q*4 + rr.
        int bT = rb >> 14, hT = (rb >> 7) & 127, wBase = rb & 127;
        size_t seqOff = (size_t)bT * 128 + hT;
        // stage tile in per-wave LDS: [w' = q*4+rr][j = n*16+l15]
#pragma unroll
        for (int n = 0; n < 4; n++)
#pragma unroll
            for (int rr = 0; rr < 4; rr++)
                lds_t[mi][wv][q * 4 + rr][n * 16 + l15] = h2us((_Float16)acc[n][rr]);
        // read back transposed: 8 consecutive lanes = one dense 128B row
#pragma unroll
        for (int k = 0; k < 2; k++){
            int wp = (lane >> 3) + k * 8;
            int j8 = (lane & 7) * 8;
            u16x8 v = *(const u16x8*)&lds_t[mi][wv][wp][j8];
            *(u16x8*)(pre + ((size_t)(wBase + wp) * NSEQ + seqOff) * 64 + j8) = v;
        }
    }
}

// ---------------------------------------------------------------------------
// k_scan<PASS>: h_t = tanh(pre_t + Whh h_{t-1}), 128 blocks x 4 waves.
// (ROUND-9 CHAMPION, byte-identical.) Wave wv owns j-tile [wv*16,+16).
// Whh/Wy f16 A-frags in VGPRs. h carried as f16. Per step: 2 rec MFMA
// (+2 Y MFMA PASS0), 4 tanh, single u16 LDS plane exchange (swizzled,
// parity dbuf) + one __syncthreads. pre slab (GT steps) reg-loaded at group
// top; outputs staged and burst-stored at group end -> barriers stay
// vmcnt-clean except once per group.
template<int PASS>
__global__ __launch_bounds__(256) void k_scan(const _Float16* __restrict__ pre,
                                              const float* __restrict__ Whh,
                                              const float* __restrict__ Wy,
                                              const float* __restrict__ by1,
                                              const float* __restrict__ by2,
                                              _Float16* __restrict__ prey,
                                              float* __restrict__ outf){
    __shared__ alignas(16) unsigned short hbuf[2][16][64];  // [par][seq][j] f16 bits
    int lane = threadIdx.x & 63;
    int wv   = threadIdx.x >> 6;
    int q = lane >> 4, l15 = lane & 15;
    int n0 = blockIdx.x * 16;
    int j0 = wv * 16 + q * 4;

    f16x8 Af[2];
#pragma unroll
    for (int kc = 0; kc < 2; kc++){
        const float* p = Whh + (wv * 16 + l15) * 64 + kc * 32 + q * 8;
#pragma unroll
        for (int i = 0; i < 8; i++)
            Af[kc][i] = (_Float16)p[i];
    }
    f16x8 Yf[2];
    f32x4 biasy = (f32x4){0.f, 0.f, 0.f, 0.f};
    if constexpr (PASS == 0){
#pragma unroll
        for (int kc = 0; kc < 2; kc++){
            const float* p = Wy + (wv * 16 + l15) * 64 + kc * 32 + q * 8;
#pragma unroll
            for (int i = 0; i < 8; i++)
                Yf[kc][i] = (_Float16)p[i];
        }
#pragma unroll
        for (int r = 0; r < 4; r++) biasy[r] = by1[j0 + r] + by2[j0 + r];
    }

    f16x8 Bf[2];
#pragma unroll
    for (int kc = 0; kc < 2; kc++)
#pragma unroll
        for (int i = 0; i < 8; i++) Bf[kc][i] = (_Float16)0.f;

    int bb = n0 >> 7, low7 = n0 & 127;   // PASS0: h0 = low7; PASS1: w0 = low7

    const _Float16* pb = pre + (size_t)(n0 + l15) * 64 + j0;
    size_t spy = (size_t)(low7 + l15) * NSEQ + (size_t)bb * 128;  // PASS0 prey seq base

    int e   = l15 & 7;
    int wj  = (((j0 >> 3) ^ e) << 3) | (j0 & 7);
    int rj0 = ((q)     ^ e) << 3;
    int rj1 = ((4 + q) ^ e) << 3;

    f16x4 ps[GT];
    u16x4 prey_st[GT];
    f32x4 outst[GT];

    for (int g = 0; g < TLEN / GT; g++){
        int G = g * GT;
#pragma unroll
        for (int u = 0; u < GT; u++)
            ps[u] = *(const f16x4*)(pb + (size_t)(G + u) * PSH);

#pragma unroll
        for (int u = 0; u < GT; u++){
            int t = G + u;
            // ---- recurrence: 2 chained f16 MFMAs (critical path)
            f32x4 a = (f32x4){(float)ps[u][0], (float)ps[u][1], (float)ps[u][2], (float)ps[u][3]};
            a = __builtin_amdgcn_mfma_f32_16x16x32_f16(Af[0], Bf[0], a, 0, 0, 0);
            a = __builtin_amdgcn_mfma_f32_16x16x32_f16(Af[1], Bf[1], a, 0, 0, 0);
            // ---- fused Y-proj on current B (= h_{t-1}) -> pre_y[t-1];
            //      independent of the a-chain, fills its latency window
            if constexpr (PASS == 0){
                f32x4 y = biasy;
                y = __builtin_amdgcn_mfma_f32_16x16x32_f16(Yf[0], Bf[0], y, 0, 0, 0);
                y = __builtin_amdgcn_mfma_f32_16x16x32_f16(Yf[1], Bf[1], y, 0, 0, 0);
#pragma unroll
                for (int r = 0; r < 4; r++)
                    prey_st[u][r] = h2us((_Float16)y[r]);
            }

            u16x4 h4;
#pragma unroll
            for (int r = 0; r < 4; r++){
                float tv = fast_tanh(a[r]);
                if constexpr (PASS == 1) outst[u][r] = tv;
                h4[r] = h2us((_Float16)tv);
            }
            int par = t & 1;
            *(u16x4*)&hbuf[par][l15][wj] = h4;
            __syncthreads();
            Bf[0] = *(const f16x8*)&hbuf[par][l15][rj0];
            Bf[1] = *(const f16x8*)&hbuf[par][l15][rj1];
        }
        // ---- burst stores (drained once at next group's first barrier)
        if constexpr (PASS == 0){
#pragma unroll
            for (int u = 0; u < GT; u++){
                int tp = G - 1 + u;
                if (tp >= 0)
                    *(u16x4*)(prey + (spy + tp) * 64 + j0) = prey_st[u];
            }
        } else {
#pragma unroll
            for (int u = 0; u < GT; u++)
#pragma unroll
                for (int r = 0; r < 4; r++)
                    outf[((size_t)(bb * 64 + j0 + r) * TLEN + (G + u)) * 128 + low7 + l15] = outst[u][r];
        }
    }
    // tail: pre_y[127] from final B (= h_127)
    if constexpr (PASS == 0){
        f32x4 y = biasy;
        y = __builtin_amdgcn_mfma_f32_16x16x32_f16(Yf[0], Bf[0], y, 0, 0, 0);
        y = __builtin_amdgcn_mfma_f32_16x16x32_f16(Yf[1], Bf[1], y, 0, 0, 0);
        u16x4 pv;
#pragma unroll
        for (int r = 0; r < 4; r++)
            pv[r] = h2us((_Float16)y[r]);
        *(u16x4*)(prey + (spy + (TLEN - 1)) * 64 + j0) = pv;
    }
}

// ---------------------------------------------------------------------------
extern "C" void kernel_launch(void* const* d_in, const int* in_sizes, int n_in,
                              void* d_out, int out_size, void* d_ws, size_t ws_size,
                              hipStream_t stream){
    (void)in_sizes; (void)n_in; (void)out_size; (void)ws_size;
    const float* x    = (const float*)d_in[0];
    const float* Wihx = (const float*)d_in[1];
    const float* Whhx = (const float*)d_in[2];
    const float* bihx = (const float*)d_in[3];
    const float* bhhx = (const float*)d_in[4];
    const float* Wihy = (const float*)d_in[5];
    const float* Whhy = (const float*)d_in[6];
    const float* bihy = (const float*)d_in[7];
    const float* bhhy = (const float*)d_in[8];
    _Float16* prex = (_Float16*)d_ws;                          // 33.5MB
    _Float16* prey = prex + (size_t)NSEQ * TLEN * 64;          // 33.5MB
    float* of = (float*)d_out;

    k_proj0 <<<2048, 256, 0, stream>>>(x, Wihx, bihx, bhhx, prex);
    k_scan<0><<<128, 256, 0, stream>>>(prex, Whhx, Wihy, bihy, bhhy, prey, nullptr);
    k_scan<1><<<128, 256, 0, stream>>>(prey, Whhy, nullptr, nullptr, nullptr, nullptr, of);
}